// Round 9
// baseline (248.338 us; speedup 1.0000x reference)
//
#include <hip/hip_runtime.h>

#define HH 192
#define WW 192
#define LL (HH * WW)   // 36864
#define CC 512
#define KK 64
#define EPSF 1e-12f
typedef unsigned long long ull;

// k3 decomposition
#define NCHUNK 192
#define CHUNKL (LL / NCHUNK)   // 192
#define LT 32
#define CT 128

// ---------------------------------------------------------------- k0: wT[c][k] = conv_w[k][c]; block 0 zeros S+rowsq
__global__ __launch_bounds__(256) void k0_transpose(const float* __restrict__ w,
                                                    float* __restrict__ wT,
                                                    float* __restrict__ Szero) {
    int idx = blockIdx.x * 256 + threadIdx.x;   // 32768 = KK*CC
    int k = idx >> 9;
    int c = idx & 511;
    wT[c * KK + k] = w[idx];
    if (blockIdx.x == 0 && threadIdx.x < 128) Szero[threadIdx.x] = 0.f;  // S[64]+rowsq[64]
}

// ---------------------------------------------------------------- k1: 512 thr, lane=pixel, wave=(k-group-16, c-half)
// (round-7 version, measured 54 us) kg/ch pinned with readfirstlane -> s_load path.
__global__ __launch_bounds__(512) void k1_logits(const float* __restrict__ x,
                                                 const float* __restrict__ wT,
                                                 float* __restrict__ soft,
                                                 float* __restrict__ invn,
                                                 ull* __restrict__ keep) {
    __shared__ float accs[4][16][64];   // 16 KB: upper-half partials
    __shared__ float sss[64];
    __shared__ float sm1[4][64], sm2[4][64], ssum[4][64], sinv[64];
    __shared__ int   si1[4][64], si2[4][64];
    int t = threadIdx.x, lane = t & 63, wid = t >> 6;   // wid 0..7
    int l0 = blockIdx.x * 64;
    int kg = __builtin_amdgcn_readfirstlane((wid & 3) * 16);
    int ch = __builtin_amdgcn_readfirstlane((wid >> 2) * 256);   // c-half base

    const float* __restrict__ xcol = x + l0 + lane;

    float acc[16];
#pragma unroll
    for (int q = 0; q < 16; ++q) acc[q] = 0.f;
    float ss = 0.f;

    float xp[16], xn[16];
#pragma unroll
    for (int q = 0; q < 16; ++q) xp[q] = xcol[(size_t)(ch + q) * LL];

    for (int cb = ch; cb < ch + 256; cb += 16) {
        if (cb + 16 < ch + 256) {
#pragma unroll
            for (int q = 0; q < 16; ++q) xn[q] = xcol[(size_t)(cb + 16 + q) * LL];
        }
#pragma unroll
        for (int cc = 0; cc < 16; ++cc) {
            float xv = xp[cc];
            ss = fmaf(xv, xv, ss);
            const float* wr = wT + (size_t)(cb + cc) * KK + kg; // uniform -> s_load
#pragma unroll
            for (int q = 0; q < 16; ++q) acc[q] = fmaf(wr[q], xv, acc[q]);
        }
        if (cb + 16 < ch + 256) {
#pragma unroll
            for (int q = 0; q < 16; ++q) xp[q] = xn[q];
        }
    }

    if (wid >= 4) {
        int w = wid - 4;
#pragma unroll
        for (int q = 0; q < 16; ++q) accs[w][q][lane] = acc[q];
        if (wid == 4) sss[lane] = ss;
    }
    __syncthreads();
    if (wid < 4) {
#pragma unroll
        for (int q = 0; q < 16; ++q) acc[q] += accs[wid][q][lane];
    }
    if (wid == 0) {
        ss += sss[lane];
        float iv = 1.0f / fmaxf(sqrtf(ss), EPSF);
        sinv[lane] = iv;
        invn[l0 + lane] = iv;
    }
    __syncthreads();
    float iv = sinv[lane];

    if (wid < 4) {
        float m1 = -3.0e38f, m2 = -3.0e38f; int i1 = 0, i2 = 0;
#pragma unroll
        for (int q = 0; q < 16; ++q) {
            float lg = acc[q] * iv;
            acc[q] = lg;
            if (lg > m1)      { m2 = m1; i2 = i1; m1 = lg; i1 = kg + q; }
            else if (lg > m2) { m2 = lg; i2 = kg + q; }
        }
        sm1[wid][lane] = m1; si1[wid][lane] = i1;
        sm2[wid][lane] = m2; si2[wid][lane] = i2;
    }
    __syncthreads();

    float M1 = -3.0e38f, M2 = -3.0e38f; int I1 = 0, I2 = 0;
    if (wid < 4) {
#pragma unroll
        for (int w2 = 0; w2 < 4; ++w2) {
            float a1 = sm1[w2][lane]; int b1 = si1[w2][lane];
            float a2 = sm2[w2][lane]; int b2 = si2[w2][lane];
            if (a1 > M1 || (a1 == M1 && b1 < I1)) { M2 = M1; I2 = I1; M1 = a1; I1 = b1; }
            else if (a1 > M2 || (a1 == M2 && b1 < I2)) { M2 = a1; I2 = b1; }
            if (a2 > M1 || (a2 == M1 && b2 < I1)) { M2 = M1; I2 = I1; M1 = a2; I1 = b2; }
            else if (a2 > M2 || (a2 == M2 && b2 < I2)) { M2 = a2; I2 = b2; }
        }
        float es = 0.f;
#pragma unroll
        for (int q = 0; q < 16; ++q) { float e = __expf(acc[q] - M1); acc[q] = e; es += e; }
        ssum[wid][lane] = es;
    }
    __syncthreads();
    if (wid < 4) {
        float St = ssum[0][lane] + ssum[1][lane] + ssum[2][lane] + ssum[3][lane];
        float rs = 1.0f / St;
        float4* sp = (float4*)(soft + (size_t)(l0 + lane) * KK + kg);
#pragma unroll
        for (int q4 = 0; q4 < 4; ++q4) {
            float4 v; v.x = acc[q4*4+0]*rs; v.y = acc[q4*4+1]*rs;
                      v.z = acc[q4*4+2]*rs; v.w = acc[q4*4+3]*rs;
            sp[q4] = v;
        }
        if (wid == 0) keep[l0 + lane] = (1ull << I1) | (1ull << I2);
    }
}

// ---------------------------------------------------------------- k3: fused weight+GEMM
// partials[ch][k][c] = sum_{l in chunk} w2(l,k) * x[c][l],  w2 = soft*cnt*bm*invn
// computed inline during w-tile staging (keep masks are wave-uniform s_loads).
// S[k] accumulated by blockIdx.y==0 blocks (unscaled sum).
__global__ __launch_bounds__(256) void k3_gemm(const float* __restrict__ soft,
                                               const ull* __restrict__ keep,
                                               const float* __restrict__ invn,
                                               const float* __restrict__ x,
                                               float* __restrict__ partials,
                                               float* __restrict__ S) {
    __shared__ float wt[LT][KK];        // row-dir b128 reads conflict-free
    __shared__ float xt[LT][CT + 4];
    __shared__ float sred[4][64];
    int chunk = blockIdx.x;             // 0..191
    int c0 = blockIdx.y * CT;           // 0..3 tiles of 128
    int l0 = chunk * CHUNKL;
    int t = threadIdx.x;
    int tx = t & 15, ty = t >> 4;       // tx->c (8), ty->k (4)
    int kk = t & 63, r2 = t >> 6;       // staging: k lane, l-row group

    float acc[4][8];
#pragma unroll
    for (int r = 0; r < 4; ++r)
#pragma unroll
        for (int s = 0; s < 8; ++s) acc[r][s] = 0.f;
    float sk = 0.f;

    for (int lb = 0; lb < CHUNKL; lb += LT) {
        // ---- stage w2 tile, computing weight on the fly ----
#pragma unroll
        for (int i2 = 0; i2 < 8; ++i2) {
            int lt = r2 + 4 * i2;
            int l = l0 + lb + lt;                  // wave-uniform
            int i = l / WW, j = l % WW;
            int m = min(min(i, HH - 1 - i), min(j, WW - 1 - j));
            float bm = (float)m; bm *= bm; bm *= bm;   // m^4
            int cnt = 0;
#pragma unroll
            for (int di = -1; di <= 1; ++di) {
                int ii = i + di;
                if (ii < 0 || ii >= HH) continue;
#pragma unroll
                for (int dj = -1; dj <= 1; ++dj) {
                    int jj = j + dj;
                    if (jj < 0 || jj >= WW) continue;
                    ull nb = keep[ii * WW + jj];   // uniform -> s_load
                    cnt += (int)((nb >> kk) & 1ull);
                }
            }
            float u = soft[(size_t)l * KK + kk] * (float)cnt * bm;  // unscaled
            sk += u;
            wt[lt][kk] = u * invn[l];
        }
        // ---- stage x tile ----
        {
            int lt2 = t & 31, cb = t >> 5;        // cb 0..7
            int gl = l0 + lb + lt2;
#pragma unroll
            for (int j = 0; j < 16; ++j)
                xt[lt2][cb + 8 * j] = x[(size_t)(c0 + cb + 8 * j) * LL + gl];
        }
        __syncthreads();
#pragma unroll 2
        for (int l2 = 0; l2 < LT; ++l2) {
            float4 wa = *(const float4*)&wt[l2][ty * 4];
            float4 xa = *(const float4*)&xt[l2][tx * 4];
            float4 xb = *(const float4*)&xt[l2][64 + tx * 4];
            float wk[4] = {wa.x, wa.y, wa.z, wa.w};
            float xs[8] = {xa.x, xa.y, xa.z, xa.w, xb.x, xb.y, xb.z, xb.w};
#pragma unroll
            for (int r = 0; r < 4; ++r)
#pragma unroll
                for (int s = 0; s < 8; ++s) acc[r][s] = fmaf(wk[r], xs[s], acc[r][s]);
        }
        __syncthreads();
    }

    // S accumulation (c-tile 0 only; sum over r2 groups)
    if (blockIdx.y == 0) {
        sred[r2][kk] = sk;
        __syncthreads();
        if (r2 == 0)
            atomicAdd(&S[kk], sred[0][kk] + sred[1][kk] + sred[2][kk] + sred[3][kk]);
    }

    float* pp = partials + (size_t)chunk * KK * CC;
#pragma unroll
    for (int r = 0; r < 4; ++r) {
        int k = ty * 4 + r;
        float4 va; va.x = acc[r][0]; va.y = acc[r][1]; va.z = acc[r][2]; va.w = acc[r][3];
        float4 vb; vb.x = acc[r][4]; vb.y = acc[r][5]; vb.z = acc[r][6]; vb.w = acc[r][7];
        *(float4*)&pp[(size_t)k * CC + c0 + tx * 4]      = va;
        *(float4*)&pp[(size_t)k * CC + c0 + 64 + tx * 4] = vb;
    }
}

// ---------------------------------------------------------------- k4a: reduce partials -> vlad, rowsq atomic
// grid (64, 4); 512 thr: tid&127 -> c, tid>>7 -> chunk quarter
__global__ __launch_bounds__(512) void k4a_reduce(const float* __restrict__ partials,
                                                  const float* __restrict__ S,
                                                  const float* __restrict__ cent,
                                                  float* __restrict__ vlad,
                                                  float* __restrict__ rowsq) {
    __shared__ float red[512];
    int k = blockIdx.x;
    int ci = threadIdx.x & 127;
    int c = blockIdx.y * 128 + ci;
    int q = threadIdx.x >> 7;                       // 0..3
    const float* pk = partials + (size_t)q * (NCHUNK / 4) * KK * CC + (size_t)k * CC + c;
    float s0 = 0.f, s1 = 0.f, s2 = 0.f, s3 = 0.f;
    for (int ch = 0; ch < NCHUNK / 4; ch += 4) {
        s0 += pk[(size_t)(ch + 0) * KK * CC];
        s1 += pk[(size_t)(ch + 1) * KK * CC];
        s2 += pk[(size_t)(ch + 2) * KK * CC];
        s3 += pk[(size_t)(ch + 3) * KK * CC];
    }
    red[threadIdx.x] = (s0 + s1) + (s2 + s3);
    __syncthreads();
    float vsq = 0.f;
    if (q == 0) {
        float v = red[ci] + red[ci + 128] + red[ci + 256] + red[ci + 384];
        v -= S[k] * cent[k * CC + c];
        vlad[k * CC + c] = v;
        vsq = v * v;
    }
    __syncthreads();
    red[threadIdx.x] = vsq;
    __syncthreads();
    for (int off = 256; off > 0; off >>= 1) {
        if (threadIdx.x < off) red[threadIdx.x] += red[threadIdx.x + off];
        __syncthreads();
    }
    if (threadIdx.x == 0) atomicAdd(&rowsq[k], red[0]);
}

// ---------------------------------------------------------------- k4c: out = vlad * rn[k], rn computed inline from rowsq
__global__ __launch_bounds__(256) void k4c_finish(const float* __restrict__ vlad,
                                                  const float* __restrict__ rowsq,
                                                  float* __restrict__ out) {
    __shared__ float rns[64];
    int t = threadIdx.x;
    if (t < 64) {
        float tot = rowsq[t];
        float r = 1.0f / fmaxf(sqrtf(tot), EPSF);
        float contrib = tot * r * r;
#pragma unroll
        for (int off = 32; off; off >>= 1) contrib += __shfl_xor(contrib, off, 64);
        float ginv = 1.0f / fmaxf(sqrtf(contrib), EPSF);
        rns[t] = r * ginv;
    }
    __syncthreads();
    int idx4 = blockIdx.x * 256 + t;               // 8192 float4s
    int k = idx4 >> 7;
    float s = rns[k];
    float4 v = ((const float4*)vlad)[idx4];
    v.x *= s; v.y *= s; v.z *= s; v.w *= s;
    ((float4*)out)[idx4] = v;
}

// ----------------------------------------------------------------
extern "C" void kernel_launch(void* const* d_in, const int* in_sizes, int n_in,
                              void* d_out, int out_size, void* d_ws, size_t ws_size,
                              hipStream_t stream) {
    const float* x      = (const float*)d_in[0];   // (512,192,192)
    const float* conv_w = (const float*)d_in[1];   // (64,512)
    const float* cent   = (const float*)d_in[2];   // (64,512)
    float* out = (float*)d_out;                    // 32768 fp32

    float* ws    = (float*)d_ws;
    float* wT    = ws;                              // 32768
    float* soft  = wT + 32768;                      // KK*LL (read-only after k1 now)
    float* invn  = soft + (size_t)KK * LL;          // 36864
    float* S     = invn + LL;                       // 64
    float* rowsq = S + KK;                          // 64  (S..rowsq contiguous 128 floats)
    float* vlad  = rowsq + KK;                      // 32768
    ull*   keep  = (ull*)(vlad + 32768);            // LL u64 (offset is 64-float multiple)
    float* partials = (float*)(keep + LL);          // NCHUNK*KK*CC floats (25.2 MB)

    k0_transpose<<<(KK * CC) / 256, 256, 0, stream>>>(conv_w, wT, S);
    k1_logits<<<LL / 64, 512, 0, stream>>>(x, wT, soft, invn, keep);
    k3_gemm<<<dim3(NCHUNK, CC / CT), 256, 0, stream>>>(soft, keep, invn, x, partials, S);
    k4a_reduce<<<dim3(KK, 4), 512, 0, stream>>>(partials, S, cent, vlad, rowsq);
    k4c_finish<<<(KK * CC / 4) / 256, 256, 0, stream>>>(vlad, rowsq, out);
}

// Round 10
// 209.764 us; speedup vs baseline: 1.1839x; 1.1839x over previous
//
#include <hip/hip_runtime.h>

#define HH 192
#define WW 192
#define LL (HH * WW)   // 36864
#define CC 512
#define KK 64
#define EPSF 1e-12f
typedef unsigned long long ull;
typedef unsigned int uint;
typedef unsigned short ushort;

// k3 decomposition
#define NCHUNK 192
#define CHUNKL (LL / NCHUNK)   // 192

typedef short bf16x8 __attribute__((ext_vector_type(8)));
typedef float f32x4 __attribute__((ext_vector_type(4)));

// ---------------------------------------------------------------- k0: wT[c][k] = conv_w[k][c]; block 0 zeros S+rowsq
__global__ __launch_bounds__(256) void k0_transpose(const float* __restrict__ w,
                                                    float* __restrict__ wT,
                                                    float* __restrict__ Szero) {
    int idx = blockIdx.x * 256 + threadIdx.x;   // 32768 = KK*CC
    int k = idx >> 9;
    int c = idx & 511;
    wT[c * KK + k] = w[idx];
    if (blockIdx.x == 0 && threadIdx.x < 128) Szero[threadIdx.x] = 0.f;  // S[64]+rowsq[64]
}

// ---------------------------------------------------------------- k1: 512 thr, lane=pixel, wave=(k-group-16, c-half)
// (round-7 version, measured 54 us) kg/ch pinned with readfirstlane -> s_load path.
__global__ __launch_bounds__(512) void k1_logits(const float* __restrict__ x,
                                                 const float* __restrict__ wT,
                                                 float* __restrict__ soft,
                                                 float* __restrict__ invn,
                                                 ull* __restrict__ keep) {
    __shared__ float accs[4][16][64];   // 16 KB: upper-half partials
    __shared__ float sss[64];
    __shared__ float sm1[4][64], sm2[4][64], ssum[4][64], sinv[64];
    __shared__ int   si1[4][64], si2[4][64];
    int t = threadIdx.x, lane = t & 63, wid = t >> 6;   // wid 0..7
    int l0 = blockIdx.x * 64;
    int kg = __builtin_amdgcn_readfirstlane((wid & 3) * 16);
    int ch = __builtin_amdgcn_readfirstlane((wid >> 2) * 256);   // c-half base

    const float* __restrict__ xcol = x + l0 + lane;

    float acc[16];
#pragma unroll
    for (int q = 0; q < 16; ++q) acc[q] = 0.f;
    float ss = 0.f;

    float xp[16], xn[16];
#pragma unroll
    for (int q = 0; q < 16; ++q) xp[q] = xcol[(size_t)(ch + q) * LL];

    for (int cb = ch; cb < ch + 256; cb += 16) {
        if (cb + 16 < ch + 256) {
#pragma unroll
            for (int q = 0; q < 16; ++q) xn[q] = xcol[(size_t)(cb + 16 + q) * LL];
        }
#pragma unroll
        for (int cc = 0; cc < 16; ++cc) {
            float xv = xp[cc];
            ss = fmaf(xv, xv, ss);
            const float* wr = wT + (size_t)(cb + cc) * KK + kg; // uniform -> s_load
#pragma unroll
            for (int q = 0; q < 16; ++q) acc[q] = fmaf(wr[q], xv, acc[q]);
        }
        if (cb + 16 < ch + 256) {
#pragma unroll
            for (int q = 0; q < 16; ++q) xp[q] = xn[q];
        }
    }

    if (wid >= 4) {
        int w = wid - 4;
#pragma unroll
        for (int q = 0; q < 16; ++q) accs[w][q][lane] = acc[q];
        if (wid == 4) sss[lane] = ss;
    }
    __syncthreads();
    if (wid < 4) {
#pragma unroll
        for (int q = 0; q < 16; ++q) acc[q] += accs[wid][q][lane];
    }
    if (wid == 0) {
        ss += sss[lane];
        float iv = 1.0f / fmaxf(sqrtf(ss), EPSF);
        sinv[lane] = iv;
        invn[l0 + lane] = iv;
    }
    __syncthreads();
    float iv = sinv[lane];

    if (wid < 4) {
        float m1 = -3.0e38f, m2 = -3.0e38f; int i1 = 0, i2 = 0;
#pragma unroll
        for (int q = 0; q < 16; ++q) {
            float lg = acc[q] * iv;
            acc[q] = lg;
            if (lg > m1)      { m2 = m1; i2 = i1; m1 = lg; i1 = kg + q; }
            else if (lg > m2) { m2 = lg; i2 = kg + q; }
        }
        sm1[wid][lane] = m1; si1[wid][lane] = i1;
        sm2[wid][lane] = m2; si2[wid][lane] = i2;
    }
    __syncthreads();

    float M1 = -3.0e38f, M2 = -3.0e38f; int I1 = 0, I2 = 0;
    if (wid < 4) {
#pragma unroll
        for (int w2 = 0; w2 < 4; ++w2) {
            float a1 = sm1[w2][lane]; int b1 = si1[w2][lane];
            float a2 = sm2[w2][lane]; int b2 = si2[w2][lane];
            if (a1 > M1 || (a1 == M1 && b1 < I1)) { M2 = M1; I2 = I1; M1 = a1; I1 = b1; }
            else if (a1 > M2 || (a1 == M2 && b1 < I2)) { M2 = a1; I2 = b1; }
            if (a2 > M1 || (a2 == M1 && b2 < I1)) { M2 = M1; I2 = I1; M1 = a2; I1 = b2; }
            else if (a2 > M2 || (a2 == M2 && b2 < I2)) { M2 = a2; I2 = b2; }
        }
        float es = 0.f;
#pragma unroll
        for (int q = 0; q < 16; ++q) { float e = __expf(acc[q] - M1); acc[q] = e; es += e; }
        ssum[wid][lane] = es;
    }
    __syncthreads();
    if (wid < 4) {
        float St = ssum[0][lane] + ssum[1][lane] + ssum[2][lane] + ssum[3][lane];
        float rs = 1.0f / St;
        float4* sp = (float4*)(soft + (size_t)(l0 + lane) * KK + kg);
#pragma unroll
        for (int q4 = 0; q4 < 4; ++q4) {
            float4 v; v.x = acc[q4*4+0]*rs; v.y = acc[q4*4+1]*rs;
                      v.z = acc[q4*4+2]*rs; v.w = acc[q4*4+3]*rs;
            sp[q4] = v;
        }
        if (wid == 0) keep[l0 + lane] = (1ull << I1) | (1ull << I2);
    }
}

// ---------------------------------------------------------------- k2: w2[l][k] = soft*cnt*border^4*invn[l] (in place), S[k] += unscaled
__global__ __launch_bounds__(256) void k2_weight(float* __restrict__ soft,
                                                 const ull* __restrict__ keep,
                                                 const float* __restrict__ invn,
                                                 float* __restrict__ S) {
    __shared__ float sred[4][64];
    int t = threadIdx.x, lane = t & 63, wid = t >> 6;
    int l0 = blockIdx.x * 32 + wid * 8;
    float sk = 0.f;
#pragma unroll
    for (int p = 0; p < 8; ++p) {
        int l = l0 + p;                           // wave-uniform
        int i = l / WW, j = l % WW;
        int m = min(min(i, HH - 1 - i), min(j, WW - 1 - j));
        float bm = (float)m; bm *= bm; bm *= bm;  // m^4
        int cnt = 0;
#pragma unroll
        for (int di = -1; di <= 1; ++di) {
            int ii = i + di;
            if (ii < 0 || ii >= HH) continue;
#pragma unroll
            for (int dj = -1; dj <= 1; ++dj) {
                int jj = j + dj;
                if (jj < 0 || jj >= WW) continue;
                ull nb = keep[ii * WW + jj];      // uniform -> s_load
                cnt += (int)((nb >> lane) & 1ull);
            }
        }
        float v = soft[(size_t)l * KK + lane];    // coalesced 256B
        float u = v * (float)cnt * bm;            // unscaled weight
        sk += u;
        soft[(size_t)l * KK + lane] = u * invn[l];
    }
    sred[wid][lane] = sk;
    __syncthreads();
    if (wid == 0)
        atomicAdd(&S[lane], sred[0][lane] + sred[1][lane] + sred[2][lane] + sred[3][lane]);
}

// ---------------------------------------------------------------- fp32 -> bf16 hi/lo pair converter (truncation; lo captures residual)
__device__ inline void cvt_pair(float v0, float v1, uint& hp, uint& lp) {
    uint b0 = __float_as_uint(v0), b1 = __float_as_uint(v1);
    uint h0 = b0 & 0xFFFF0000u, h1 = b1 & 0xFFFF0000u;
    float r0 = v0 - __uint_as_float(h0);
    float r1 = v1 - __uint_as_float(h1);
    hp = (h0 >> 16) | h1;
    lp = (__float_as_uint(r0) >> 16) | (__float_as_uint(r1) & 0xFFFF0000u);
}

// ---------------------------------------------------------------- k3: MFMA GEMM, bf16 3-term split
// partials[ch][k][c] = sum_{l in chunk} w2[l][k] * x[c][l]
// block 256 thr = 4 waves; tile 64k x 128c; wave c-slice 32; K-step 32 l.
// A = w2^T staged [k][l] bf16 hi/lo; B = x staged [c][l] bf16 hi/lo.
// Frag layouts per m97 conventions: lane&15=row, (lane>>4)*8=K-offset, 8 K-contig per lane.
__global__ __launch_bounds__(256) void k3_mfma(const float* __restrict__ w2,
                                               const float* __restrict__ x,
                                               float* __restrict__ partials) {
    __shared__ ushort wa_hi[64][40], wa_lo[64][40];     // 10 KB
    __shared__ ushort xb_hi[128][40], xb_lo[128][40];   // 20.5 KB
    int chunk = blockIdx.x;             // 0..191
    int c0 = blockIdx.y * 128;          // 0..3
    int l0 = chunk * CHUNKL;
    int t = threadIdx.x, lane = t & 63, wid = t >> 6;
    int m = lane & 15, quad = lane >> 4;

    f32x4 acc[4][2];
#pragma unroll
    for (int kg = 0; kg < 4; ++kg)
#pragma unroll
        for (int cg = 0; cg < 2; ++cg) acc[kg][cg] = (f32x4){0.f, 0.f, 0.f, 0.f};

    for (int lb = 0; lb < CHUNKL; lb += 32) {
        // ---- stage w2 (64k x 32l) -> wa[k][l], transposed, l-pairs packed as dwords ----
        {
            int k = t & 63, rg = t >> 6;            // rg 0..3
#pragma unroll
            for (int i = 0; i < 4; ++i) {
                int lp = rg + 4 * i;                // pair index 0..15
                int gl = l0 + lb + 2 * lp;
                float v0 = w2[(size_t)gl * KK + k];         // coalesced 256B rows
                float v1 = w2[(size_t)(gl + 1) * KK + k];
                uint hp, lq;
                cvt_pair(v0, v1, hp, lq);
                *(uint*)&wa_hi[k][2 * lp] = hp;
                *(uint*)&wa_lo[k][2 * lp] = lq;
            }
        }
        // ---- stage x (128c x 32l) -> xb[c][l], l-pairs packed ----
        {
            int lp = t & 15, cb = t >> 4;           // cb 0..15
            int gl = l0 + lb + 2 * lp;
#pragma unroll
            for (int i = 0; i < 8; ++i) {
                int c = cb + 16 * i;
                float v0 = x[(size_t)(c0 + c) * LL + gl];   // coalesced along l
                float v1 = x[(size_t)(c0 + c) * LL + gl + 1];
                uint hp, lq;
                cvt_pair(v0, v1, hp, lq);
                *(uint*)&xb_hi[c][2 * lp] = hp;
                *(uint*)&xb_lo[c][2 * lp] = lq;
            }
        }
        __syncthreads();
        // ---- fragments + MFMA ----
        bf16x8 Ah[4], Al[4];
#pragma unroll
        for (int kg = 0; kg < 4; ++kg) {
            Ah[kg] = *(bf16x8*)&wa_hi[kg * 16 + m][quad * 8];
            Al[kg] = *(bf16x8*)&wa_lo[kg * 16 + m][quad * 8];
        }
#pragma unroll
        for (int cg = 0; cg < 2; ++cg) {
            int crow = wid * 32 + cg * 16 + m;
            bf16x8 Bh = *(bf16x8*)&xb_hi[crow][quad * 8];
            bf16x8 Bl = *(bf16x8*)&xb_lo[crow][quad * 8];
#pragma unroll
            for (int kg = 0; kg < 4; ++kg) {
                acc[kg][cg] = __builtin_amdgcn_mfma_f32_16x16x32_bf16(Ah[kg], Bh, acc[kg][cg], 0, 0, 0);
                acc[kg][cg] = __builtin_amdgcn_mfma_f32_16x16x32_bf16(Ah[kg], Bl, acc[kg][cg], 0, 0, 0);
                acc[kg][cg] = __builtin_amdgcn_mfma_f32_16x16x32_bf16(Al[kg], Bh, acc[kg][cg], 0, 0, 0);
            }
        }
        __syncthreads();
    }
    // ---- store: D row = kg*16 + quad*4 + r, col = c0 + wid*32 + cg*16 + m ----
    float* pp = partials + (size_t)chunk * KK * CC;
#pragma unroll
    for (int kg = 0; kg < 4; ++kg)
#pragma unroll
        for (int cg = 0; cg < 2; ++cg) {
            int cout = c0 + wid * 32 + cg * 16 + m;
#pragma unroll
            for (int r = 0; r < 4; ++r) {
                int kout = kg * 16 + quad * 4 + r;
                pp[(size_t)kout * CC + cout] = acc[kg][cg][r];
            }
        }
}

// ---------------------------------------------------------------- k4a: reduce partials -> vlad, rowsq atomic
__global__ __launch_bounds__(512) void k4a_reduce(const float* __restrict__ partials,
                                                  const float* __restrict__ S,
                                                  const float* __restrict__ cent,
                                                  float* __restrict__ vlad,
                                                  float* __restrict__ rowsq) {
    __shared__ float red[512];
    int k = blockIdx.x;
    int ci = threadIdx.x & 127;
    int c = blockIdx.y * 128 + ci;
    int q = threadIdx.x >> 7;                       // 0..3
    const float* pk = partials + (size_t)q * (NCHUNK / 4) * KK * CC + (size_t)k * CC + c;
    float s0 = 0.f, s1 = 0.f, s2 = 0.f, s3 = 0.f;
    for (int ch = 0; ch < NCHUNK / 4; ch += 4) {
        s0 += pk[(size_t)(ch + 0) * KK * CC];
        s1 += pk[(size_t)(ch + 1) * KK * CC];
        s2 += pk[(size_t)(ch + 2) * KK * CC];
        s3 += pk[(size_t)(ch + 3) * KK * CC];
    }
    red[threadIdx.x] = (s0 + s1) + (s2 + s3);
    __syncthreads();
    float vsq = 0.f;
    if (q == 0) {
        float v = red[ci] + red[ci + 128] + red[ci + 256] + red[ci + 384];
        v -= S[k] * cent[k * CC + c];
        vlad[k * CC + c] = v;
        vsq = v * v;
    }
    __syncthreads();
    red[threadIdx.x] = vsq;
    __syncthreads();
    for (int off = 256; off > 0; off >>= 1) {
        if (threadIdx.x < off) red[threadIdx.x] += red[threadIdx.x + off];
        __syncthreads();
    }
    if (threadIdx.x == 0) atomicAdd(&rowsq[k], red[0]);
}

// ---------------------------------------------------------------- k4c: out = vlad * rn[k], rn computed inline from rowsq
__global__ __launch_bounds__(256) void k4c_finish(const float* __restrict__ vlad,
                                                  const float* __restrict__ rowsq,
                                                  float* __restrict__ out) {
    __shared__ float rns[64];
    int t = threadIdx.x;
    if (t < 64) {
        float tot = rowsq[t];
        float r = 1.0f / fmaxf(sqrtf(tot), EPSF);
        float contrib = tot * r * r;
#pragma unroll
        for (int off = 32; off; off >>= 1) contrib += __shfl_xor(contrib, off, 64);
        float ginv = 1.0f / fmaxf(sqrtf(contrib), EPSF);
        rns[t] = r * ginv;
    }
    __syncthreads();
    int idx4 = blockIdx.x * 256 + t;               // 8192 float4s
    int k = idx4 >> 7;
    float s = rns[k];
    float4 v = ((const float4*)vlad)[idx4];
    v.x *= s; v.y *= s; v.z *= s; v.w *= s;
    ((float4*)out)[idx4] = v;
}

// ----------------------------------------------------------------
extern "C" void kernel_launch(void* const* d_in, const int* in_sizes, int n_in,
                              void* d_out, int out_size, void* d_ws, size_t ws_size,
                              hipStream_t stream) {
    const float* x      = (const float*)d_in[0];   // (512,192,192)
    const float* conv_w = (const float*)d_in[1];   // (64,512)
    const float* cent   = (const float*)d_in[2];   // (64,512)
    float* out = (float*)d_out;                    // 32768 fp32

    float* ws    = (float*)d_ws;
    float* wT    = ws;                              // 32768
    float* soft  = wT + 32768;                      // KK*LL (becomes w2 in place)
    float* invn  = soft + (size_t)KK * LL;          // 36864
    float* S     = invn + LL;                       // 64
    float* rowsq = S + KK;                          // 64  (S..rowsq contiguous 128 floats)
    float* vlad  = rowsq + KK;                      // 32768
    ull*   keep  = (ull*)(vlad + 32768);            // LL u64
    float* partials = (float*)(keep + LL);          // NCHUNK*KK*CC floats (25.2 MB)

    k0_transpose<<<(KK * CC) / 256, 256, 0, stream>>>(conv_w, wT, S);
    k1_logits<<<LL / 64, 512, 0, stream>>>(x, wT, soft, invn, keep);
    k2_weight<<<LL / 32, 256, 0, stream>>>(soft, keep, invn, S);
    k3_mfma<<<dim3(NCHUNK, 4), 256, 0, stream>>>(soft, x, partials);
    k4a_reduce<<<dim3(KK, 4), 512, 0, stream>>>(partials, S, cent, vlad, rowsq);
    k4c_finish<<<(KK * CC / 4) / 256, 256, 0, stream>>>(vlad, rowsq, out);
}